// Round 1
// baseline (7481.345 us; speedup 1.0000x reference)
//
#include <hip/hip_runtime.h>
#include <math.h>

// Problem constants (from reference): V=4096, E=12288, NI=3900, B=64
#define NI_  3900
#define NIP  3904   // NI padded to multiple of 64
#define E_   12288
#define B_   64
#define V_   4096
#define NIT  32     // fixed CG iterations (kappa ~ 13 -> ~1e-8 rel. error)
#define KSPLIT 4
#define KCH  (NIP / KSPLIT)   // 976 rows of k per split

// ---------------------------------------------------------------------------
// sw[e] = sqrt(weights[e])
__global__ void k_sw(const float* __restrict__ w, float* __restrict__ sw) {
    int e = blockIdx.x * blockDim.x + threadIdx.x;
    if (e < E_) sw[e] = sqrtf(w[e]);
}

// b[i*64+c] = X[c, ii[i]] / star0_inv[ii[i]]   (rhs of the SPD system)
// r = p = b  (x starts at 0 via memset)
__global__ void k_init(const float* __restrict__ X, const float* __restrict__ s0i,
                       const int* __restrict__ ii,
                       float* __restrict__ b, float* __restrict__ r, float* __restrict__ p) {
    int idx = blockIdx.x * blockDim.x + threadIdx.x;
    if (idx >= NIP * B_) return;
    int i = idx >> 6, c = idx & 63;
    float v = 0.f;
    if (i < NI_) {
        int g = ii[i];
        v = X[(size_t)c * V_ + g] / s0i[g];
    }
    b[idx] = v; r[idx] = v; p[idx] = v;
}

// ---------------------------------------------------------------------------
// S[i,j] = sum_e w[e] * d0[e, ii[i]] * d0[e, ii[j]]  for i,j < NI (0 padded).
// 64x64 tile per block, 256 threads, 4x4 acc per thread, BK=16.
// Symmetry: only blocks with bj >= bi compute; mirror-write the transpose.
__global__ __launch_bounds__(256) void k_gemm(const float* __restrict__ d0,
                                              const float* __restrict__ sw,
                                              const int* __restrict__ ii,
                                              float* __restrict__ S) {
    int bi = blockIdx.y, bj = blockIdx.x;
    if (bj < bi) return;
    __shared__ float As[16][64];
    __shared__ float Bs[16][64];
    int t = threadIdx.x;
    int tx = t & 15, ty = t >> 4;
    int lrow = t >> 4;            // staging row within k-tile (0..15)
    int lcol = (t & 15) * 4;      // staging col (0..60 step 4)
    int gi = bi * 64, gj = bj * 64;

    // hoist gather indices (fixed per thread across the k loop)
    int gca[4], gcb[4];
#pragma unroll
    for (int u = 0; u < 4; ++u) {
        int ca = gi + lcol + u;
        gca[u] = (ca < NI_) ? ii[ca] : -1;
        int cb = gj + lcol + u;
        gcb[u] = (cb < NI_) ? ii[cb] : -1;
    }

    float acc[4][4] = {};
    for (int k0 = 0; k0 < E_; k0 += 16) {
        float s = sw[k0 + lrow];
        const float* row = d0 + (size_t)(k0 + lrow) * V_;
#pragma unroll
        for (int u = 0; u < 4; ++u) {
            As[lrow][lcol + u] = (gca[u] >= 0) ? s * row[gca[u]] : 0.f;
            Bs[lrow][lcol + u] = (gcb[u] >= 0) ? s * row[gcb[u]] : 0.f;
        }
        __syncthreads();
#pragma unroll
        for (int kk = 0; kk < 16; ++kk) {
            float4 a  = *(const float4*)&As[kk][ty * 4];
            float4 bv = *(const float4*)&Bs[kk][tx * 4];
            float av[4] = {a.x, a.y, a.z, a.w};
            float bw[4] = {bv.x, bv.y, bv.z, bv.w};
#pragma unroll
            for (int u = 0; u < 4; ++u)
#pragma unroll
                for (int v = 0; v < 4; ++v)
                    acc[u][v] += av[u] * bw[v];
        }
        __syncthreads();
    }
    // write tile (gi.., gj..)
#pragma unroll
    for (int u = 0; u < 4; ++u) {
        float4 vv = make_float4(acc[u][0], acc[u][1], acc[u][2], acc[u][3]);
        *(float4*)&S[(size_t)(gi + ty * 4 + u) * NIP + gj + tx * 4] = vv;
    }
    if (bi != bj) {   // mirror: S[gj.., gi..] = tile^T
#pragma unroll
        for (int v = 0; v < 4; ++v) {
            float4 vv = make_float4(acc[0][v], acc[1][v], acc[2][v], acc[3][v]);
            *(float4*)&S[(size_t)(gj + tx * 4 + v) * NIP + gi + ty * 4] = vv;
        }
    }
}

// S[i,i] += 1/star0_inv[ii[i]]
__global__ void k_diag(const float* __restrict__ s0i, const int* __restrict__ ii,
                       float* __restrict__ S) {
    int i = blockIdx.x * blockDim.x + threadIdx.x;
    if (i < NI_) S[(size_t)i * NIP + i] += 1.0f / s0i[ii[i]];
}

// ---------------------------------------------------------------------------
// Sp += S[rows bi*64..][kchunk] @ p   (partial over k, atomicAdd combine)
__global__ __launch_bounds__(256) void k_mv(const float* __restrict__ S,
                                            const float* __restrict__ p,
                                            float* __restrict__ Sp) {
    int bi = blockIdx.x;      // row tile 0..60
    int ks = blockIdx.y;      // k split 0..KSPLIT-1
    __shared__ float Ps[16][64];
    __shared__ float Ss[64][20];   // padded to kill 4-way bank conflicts
    int t = threadIdx.x;
    int tx = t & 15, ty = t >> 4;
    int i0 = bi * 64;
    float acc[4][4] = {};
    for (int kb = ks * KCH; kb < (ks + 1) * KCH; kb += 16) {
        {   // stage p tile: 16 k x 64 c
            int kr = t >> 4, c4 = (t & 15) * 4;
            *(float4*)&Ps[kr][c4] = *(const float4*)&p[(size_t)(kb + kr) * 64 + c4];
        }
        {   // stage S tile: 64 i x 16 k
            int ir = t >> 2, k4 = (t & 3) * 4;
            *(float4*)&Ss[ir][k4] = *(const float4*)&S[(size_t)(i0 + ir) * NIP + kb + k4];
        }
        __syncthreads();
#pragma unroll
        for (int kk = 0; kk < 16; ++kk) {
            float4 pv = *(const float4*)&Ps[kk][tx * 4];
            float pw[4] = {pv.x, pv.y, pv.z, pv.w};
            float sv[4];
#pragma unroll
            for (int u = 0; u < 4; ++u) sv[u] = Ss[ty * 4 + u][kk];
#pragma unroll
            for (int u = 0; u < 4; ++u)
#pragma unroll
                for (int v = 0; v < 4; ++v)
                    acc[u][v] += sv[u] * pw[v];
        }
        __syncthreads();
    }
#pragma unroll
    for (int u = 0; u < 4; ++u)
#pragma unroll
        for (int v = 0; v < 4; ++v)
            atomicAdd(&Sp[(size_t)(i0 + ty * 4 + u) * 64 + tx * 4 + v], acc[u][v]);
}

// out[c] += sum_i a[i,c]*b[i,c]   (per-batch-column dot, atomic combine)
__global__ void k_dot(const float* __restrict__ a, const float* __restrict__ b,
                      float* __restrict__ out) {
    __shared__ float red[4][64];
    int t = threadIdx.x;
    int c = t & 63, g = t >> 6;
    float acc = 0.f;
    for (int i = blockIdx.x * 4 + g; i < NIP; i += gridDim.x * 4) {
        size_t o = (size_t)i * 64 + c;
        acc += a[o] * b[o];
    }
    red[g][c] = acc;
    __syncthreads();
    if (g == 0) atomicAdd(&out[c], red[0][c] + red[1][c] + red[2][c] + red[3][c]);
}

// alpha = rr_old/pAp; x += alpha p; r -= alpha Sp; rr_new[c] += sum r^2
__global__ void k_xr(const float* __restrict__ rr_old, const float* __restrict__ pAp,
                     const float* __restrict__ p, const float* __restrict__ Sp,
                     float* __restrict__ x, float* __restrict__ r,
                     float* __restrict__ rr_new) {
    __shared__ float red[4][64];
    int t = threadIdx.x;
    int c = t & 63, g = t >> 6;
    float alpha = rr_old[c] / (pAp[c] + 1e-30f);
    float acc = 0.f;
    for (int i = blockIdx.x * 4 + g; i < NIP; i += gridDim.x * 4) {
        size_t o = (size_t)i * 64 + c;
        x[o] += alpha * p[o];
        float rn = r[o] - alpha * Sp[o];
        r[o] = rn;
        acc += rn * rn;
    }
    red[g][c] = acc;
    __syncthreads();
    if (g == 0) atomicAdd(&rr_new[c], red[0][c] + red[1][c] + red[2][c] + red[3][c]);
}

// beta = rr_new/rr_old; p = r + beta p
__global__ void k_p(const float* __restrict__ rr_new, const float* __restrict__ rr_old,
                    const float* __restrict__ r, float* __restrict__ p) {
    int idx = blockIdx.x * blockDim.x + threadIdx.x;
    if (idx >= NIP * B_) return;
    int c = idx & 63;
    float beta = rr_new[c] / (rr_old[c] + 1e-30f);
    p[idx] = r[idx] + beta * p[idx];
}

// out[c, i] = x[i, c]
__global__ void k_out(const float* __restrict__ x, float* __restrict__ out) {
    int idx = blockIdx.x * blockDim.x + threadIdx.x;
    if (idx >= B_ * NI_) return;
    int c = idx / NI_, i = idx - c * NI_;
    out[idx] = x[(size_t)i * 64 + c];
}

// ---------------------------------------------------------------------------
extern "C" void kernel_launch(void* const* d_in, const int* in_sizes, int n_in,
                              void* d_out, int out_size, void* d_ws, size_t ws_size,
                              hipStream_t stream) {
    const float* X   = (const float*)d_in[0];
    const float* d0  = (const float*)d_in[1];
    const float* w   = (const float*)d_in[2];
    const float* s0i = (const float*)d_in[3];
    const int*   ii  = (const int*)d_in[4];
    float* out = (float*)d_out;

    float* ws = (float*)d_ws;
    size_t off = 0;
    float* S   = ws + off;  off += (size_t)NIP * NIP;   // 15,241,216 f
    float* b   = ws + off;  off += (size_t)NIP * B_;
    float* x   = ws + off;  off += (size_t)NIP * B_;
    float* r   = ws + off;  off += (size_t)NIP * B_;
    float* p   = ws + off;  off += (size_t)NIP * B_;
    float* Sp  = ws + off;  off += (size_t)NIP * B_;
    float* pAp = ws + off;  off += 64;
    float* rr  = ws + off;  off += 128;                 // rr[0..63], rr[64..127]
    float* sw  = ws + off;  off += E_;
    size_t needed_bytes = off * sizeof(float);          // ~66 MB
    if (ws_size < needed_bytes) return;  // output stays poisoned -> visible fail

    // zero b..rr region (x must start at 0; dot accumulators must start at 0)
    hipMemsetAsync(b, 0, ((size_t)5 * NIP * B_ + 192) * sizeof(float), stream);

    k_sw<<<(E_ + 255) / 256, 256, 0, stream>>>(w, sw);
    k_init<<<(NIP * B_ + 255) / 256, 256, 0, stream>>>(X, s0i, ii, b, r, p);

    dim3 gg(NIP / 64, NIP / 64);   // 61 x 61, lower triangle early-exits
    k_gemm<<<gg, 256, 0, stream>>>(d0, sw, ii, S);
    k_diag<<<(NI_ + 255) / 256, 256, 0, stream>>>(s0i, ii, S);

    k_dot<<<64, 256, 0, stream>>>(b, b, rr);   // rr[0] = ||r0||^2 per column

    for (int it = 0; it < NIT; ++it) {
        float* rro = rr + (it & 1) * 64;
        float* rrn = rr + ((it & 1) ^ 1) * 64;
        // zero Sp and pAp (contiguous), and rr_new
        hipMemsetAsync(Sp, 0, ((size_t)NIP * B_ + 64) * sizeof(float), stream);
        hipMemsetAsync(rrn, 0, 64 * sizeof(float), stream);
        k_mv<<<dim3(NIP / 64, KSPLIT), 256, 0, stream>>>(S, p, Sp);
        k_dot<<<64, 256, 0, stream>>>(p, Sp, pAp);
        k_xr<<<128, 256, 0, stream>>>(rro, pAp, p, Sp, x, r, rrn);
        k_p<<<(NIP * B_ + 255) / 256, 256, 0, stream>>>(rrn, rro, r, p);
    }

    k_out<<<(B_ * NI_ + 255) / 256, 256, 0, stream>>>(x, out);
}

// Round 2
// 7449.203 us; speedup vs baseline: 1.0043x; 1.0043x over previous
//
#include <hip/hip_runtime.h>
#include <math.h>

// V=4096, E=12288, NI=3900, B=64
#define NI_   3900
#define NIPP  3968            // NI padded to multiple of 128
#define E_    12288
#define B_    64
#define V_    4096
#define NIT   24              // CG iterations (kappa ~13)

typedef _Float16 f16x8 __attribute__((ext_vector_type(8)));
typedef float    f32x4 __attribute__((ext_vector_type(4)));

// ---------------------------------------------------------------------------
__global__ void k_sw(const float* __restrict__ w, float* __restrict__ sw) {
    int e = blockIdx.x * blockDim.x + threadIdx.x;
    if (e < E_) sw[e] = sqrtf(w[e]);
}

// r = b = X[:,ii].T / s0i[ii];  ph = f16(r);  x = 0; Sp = 0; rr0[c] = sum r^2
__global__ void k_init(const float* __restrict__ X, const float* __restrict__ s0i,
                       const int* __restrict__ ii,
                       float* __restrict__ r, _Float16* __restrict__ ph,
                       float* __restrict__ x, float* __restrict__ Sp,
                       float* __restrict__ rr0) {
    __shared__ float red[4][64];
    int t = threadIdx.x, c = t & 63, g = t >> 6;
    float acc = 0.f;
    for (int i = blockIdx.x * 4 + g; i < NIPP; i += gridDim.x * 4) {
        float v = 0.f;
        if (i < NI_) { int gg = ii[i]; v = X[(size_t)c * V_ + gg] / s0i[gg]; }
        size_t o = (size_t)i * 64 + c;
        r[o] = v; ph[o] = (_Float16)v; x[o] = 0.f; Sp[o] = 0.f;
        acc += v * v;
    }
    red[g][c] = acc; __syncthreads();
    if (g == 0) atomicAdd(&rr0[c], red[0][c] + red[1][c] + red[2][c] + red[3][c]);
}

// ---------------------------------------------------------------------------
// Sh[i,j] = sum_e w[e] * d0[e, ii[i]] * d0[e, ii[j]]   (f16 output, both triangles)
// 128x128 tile / block, 256 thr = 4 waves (2x2 of 64x64), BK=64, f16 MFMA.
__global__ __launch_bounds__(256) void k_gemm(const float* __restrict__ d0,
                                              const float* __restrict__ sw,
                                              const int* __restrict__ ii,
                                              _Float16* __restrict__ Sh) {
    int bi = blockIdx.y, bj = blockIdx.x;
    if (bj < bi) return;
    __shared__ _Float16 TA[128 * 64];   // [col][k] xor-swizzled, 16KB
    __shared__ _Float16 TB[128 * 64];
    int t = threadIdx.x;
    int l = t & 63, w = t >> 6;
    int sc = t & 127, sh = t >> 7;                 // staging: col, k-half
    int gi = bi * 128, gj = bj * 128;
    int colA = (gi + sc < NI_) ? ii[gi + sc] : -1;
    int colB = (gj + sc < NI_) ? ii[gj + sc] : -1;
    int wr = (w >> 1) * 64, wc = (w & 1) * 64;     // wave tile origin

    f32x4 acc[4][4] = {};

    for (int k0 = 0; k0 < E_; k0 += 64) {
#pragma unroll
        for (int p = 0; p < 4; ++p) {              // stage 64k x 128c per tile
            int kb = p * 2 + sh;                   // 16B granule 0..7
            int kg = k0 + kb * 8;
            f16x8 va, vb;
#pragma unroll
            for (int j = 0; j < 8; ++j) {
                float s = sw[kg + j];
                const float* row = d0 + (size_t)(kg + j) * V_;
                va[j] = (_Float16)(colA >= 0 ? s * row[colA] : 0.f);
                vb[j] = (_Float16)(colB >= 0 ? s * row[colB] : 0.f);
            }
            *(f16x8*)&TA[sc * 64 + ((kb ^ (sc & 7)) << 3)] = va;
            *(f16x8*)&TB[sc * 64 + ((kb ^ (sc & 7)) << 3)] = vb;
        }
        __syncthreads();
#pragma unroll
        for (int kk = 0; kk < 2; ++kk) {
            int kb = kk * 4 + (l >> 4);
            f16x8 a[4], b[4];
#pragma unroll
            for (int f = 0; f < 4; ++f) {
                int i = wr + f * 16 + (l & 15);
                a[f] = *(const f16x8*)&TA[i * 64 + ((kb ^ (i & 7)) << 3)];
                int j = wc + f * 16 + (l & 15);
                b[f] = *(const f16x8*)&TB[j * 64 + ((kb ^ (j & 7)) << 3)];
            }
#pragma unroll
            for (int fm = 0; fm < 4; ++fm)
#pragma unroll
                for (int fn = 0; fn < 4; ++fn)
                    acc[fm][fn] = __builtin_amdgcn_mfma_f32_16x16x32_f16(
                        a[fm], b[fn], acc[fm][fn], 0, 0, 0);
        }
        __syncthreads();
    }
    // C/D layout: col = l&15, row = (l>>4)*4 + q  (guide-verified)
#pragma unroll
    for (int fm = 0; fm < 4; ++fm)
#pragma unroll
        for (int fn = 0; fn < 4; ++fn)
#pragma unroll
            for (int q = 0; q < 4; ++q) {
                int r = gi + wr + fm * 16 + (l >> 4) * 4 + q;
                int c = gj + wc + fn * 16 + (l & 15);
                _Float16 v = (_Float16)acc[fm][fn][q];
                Sh[(size_t)r * NIPP + c] = v;
                if (bi != bj) Sh[(size_t)c * NIPP + r] = v;
            }
}

// Sh[i,i] += 1/s0i[ii[i]]  (padded rows get identity)
__global__ void k_diag(const float* __restrict__ s0i, const int* __restrict__ ii,
                       _Float16* __restrict__ Sh) {
    int i = blockIdx.x * blockDim.x + threadIdx.x;
    if (i >= NIPP) return;
    float add = (i < NI_) ? 1.0f / s0i[ii[i]] : 1.0f;
    size_t o = (size_t)i * NIPP + i;
    Sh[o] = (_Float16)((float)Sh[o] + add);
}

// ---------------------------------------------------------------------------
// Sp += Sh[rows 128*bi ..][kchunk] @ ph   (f16 MFMA; A-frags direct from global)
__global__ __launch_bounds__(256) void k_mvf(const _Float16* __restrict__ Sh,
                                             const _Float16* __restrict__ ph,
                                             float* __restrict__ Sp) {
    int bi = blockIdx.x;          // 31 row tiles of 128
    int ks = blockIdx.y;          // 2 k-splits of 1984
    __shared__ _Float16 PT[64 * 64];   // p transposed [c][k], swizzled
    int t = threadIdx.x;
    int l = t & 63, w = t >> 6;
    int r0 = bi * 128 + w * 32;
    int sc = t & 63, sq = t >> 6;
    f32x4 acc[2][4] = {};
    for (int k0 = ks * 1984; k0 < ks * 1984 + 1984; k0 += 64) {
#pragma unroll
        for (int p = 0; p < 2; ++p) {
            int kb = p * 4 + sq;
            f16x8 v;
#pragma unroll
            for (int j = 0; j < 8; ++j)
                v[j] = ph[(size_t)(k0 + kb * 8 + j) * 64 + sc];
            *(f16x8*)&PT[sc * 64 + ((kb ^ (sc & 7)) << 3)] = v;
        }
        __syncthreads();
#pragma unroll
        for (int kk = 0; kk < 2; ++kk) {
            int kb = kk * 4 + (l >> 4);
            int kg = k0 + kk * 32 + (l >> 4) * 8;
            f16x8 a[2], b[4];
#pragma unroll
            for (int f = 0; f < 2; ++f)
                a[f] = *(const f16x8*)&Sh[(size_t)(r0 + f * 16 + (l & 15)) * NIPP + kg];
#pragma unroll
            for (int f = 0; f < 4; ++f) {
                int j = f * 16 + (l & 15);
                b[f] = *(const f16x8*)&PT[j * 64 + ((kb ^ (j & 7)) << 3)];
            }
#pragma unroll
            for (int fm = 0; fm < 2; ++fm)
#pragma unroll
                for (int fn = 0; fn < 4; ++fn)
                    acc[fm][fn] = __builtin_amdgcn_mfma_f32_16x16x32_f16(
                        a[fm], b[fn], acc[fm][fn], 0, 0, 0);
        }
        __syncthreads();
    }
#pragma unroll
    for (int fm = 0; fm < 2; ++fm)
#pragma unroll
        for (int fn = 0; fn < 4; ++fn)
#pragma unroll
            for (int q = 0; q < 4; ++q) {
                int r = r0 + fm * 16 + (l >> 4) * 4 + q;
                int c = fn * 16 + (l & 15);
                atomicAdd(&Sp[(size_t)r * 64 + c], acc[fm][fn][q]);
            }
}

// out[c] += sum_i ph[i,c]*Sp[i,c]
__global__ void k_dot(const _Float16* __restrict__ a, const float* __restrict__ b,
                      float* __restrict__ out) {
    __shared__ float red[4][64];
    int t = threadIdx.x, c = t & 63, g = t >> 6;
    float acc = 0.f;
    for (int i = blockIdx.x * 4 + g; i < NIPP; i += gridDim.x * 4) {
        size_t o = (size_t)i * 64 + c;
        acc += (float)a[o] * b[o];
    }
    red[g][c] = acc; __syncthreads();
    if (g == 0) atomicAdd(&out[c], red[0][c] + red[1][c] + red[2][c] + red[3][c]);
}

// alpha = rro/pAp; x += alpha*ph; r -= alpha*Sp; rrn[c] += sum r^2
__global__ void k_xr(const float* __restrict__ rro, const float* __restrict__ pApd,
                     const _Float16* __restrict__ ph, const float* __restrict__ Sp,
                     float* __restrict__ x, float* __restrict__ r,
                     float* __restrict__ rrn) {
    __shared__ float red[4][64];
    int t = threadIdx.x, c = t & 63, g = t >> 6;
    float alpha = rro[c] / (pApd[c] + 1e-30f);
    float acc = 0.f;
    for (int i = blockIdx.x * 4 + g; i < NIPP; i += gridDim.x * 4) {
        size_t o = (size_t)i * 64 + c;
        x[o] += alpha * (float)ph[o];
        float rn = r[o] - alpha * Sp[o];
        r[o] = rn;
        acc += rn * rn;
    }
    red[g][c] = acc; __syncthreads();
    if (g == 0) atomicAdd(&rrn[c], red[0][c] + red[1][c] + red[2][c] + red[3][c]);
}

// beta = rrn/rro; ph = f16(r + beta*ph); Sp = 0 (for next iter)
__global__ void k_p(const float* __restrict__ rrn, const float* __restrict__ rro,
                    const float* __restrict__ r, _Float16* __restrict__ ph,
                    float* __restrict__ Sp) {
    int idx = blockIdx.x * blockDim.x + threadIdx.x;
    if (idx >= NIPP * B_) return;
    int c = idx & 63;
    float beta = rrn[c] / (rro[c] + 1e-30f);
    ph[idx] = (_Float16)(r[idx] + beta * (float)ph[idx]);
    Sp[idx] = 0.f;
}

// out[c, i] = x[i, c]
__global__ void k_out(const float* __restrict__ x, float* __restrict__ out) {
    int idx = blockIdx.x * blockDim.x + threadIdx.x;
    if (idx >= B_ * NI_) return;
    int c = idx / NI_, i = idx - c * NI_;
    out[idx] = x[(size_t)i * 64 + c];
}

// ---------------------------------------------------------------------------
extern "C" void kernel_launch(void* const* d_in, const int* in_sizes, int n_in,
                              void* d_out, int out_size, void* d_ws, size_t ws_size,
                              hipStream_t stream) {
    const float* X   = (const float*)d_in[0];
    const float* d0  = (const float*)d_in[1];
    const float* w   = (const float*)d_in[2];
    const float* s0i = (const float*)d_in[3];
    const int*   ii  = (const int*)d_in[4];
    float* out = (float*)d_out;

    char* ws = (char*)d_ws;
    size_t off = 0;
    _Float16* Sh = (_Float16*)(ws + off); off += (size_t)NIPP * NIPP * 2;  // 31.5MB
    _Float16* ph = (_Float16*)(ws + off); off += (size_t)NIPP * B_ * 2;
    float* Sp = (float*)(ws + off); off += (size_t)NIPP * B_ * 4;
    float* x  = (float*)(ws + off); off += (size_t)NIPP * B_ * 4;
    float* r  = (float*)(ws + off); off += (size_t)NIPP * B_ * 4;
    float* sw = (float*)(ws + off); off += (size_t)E_ * 4;
    float* rr  = (float*)(ws + off); off += (size_t)(NIT + 1) * 64 * 4;
    float* pAp = (float*)(ws + off); off += (size_t)NIT * 64 * 4;
    if (ws_size < off) return;   // clean failure signal

    // zero the slotted reduction accumulators once (rr + pAp contiguous)
    hipMemsetAsync(rr, 0, (size_t)(2 * NIT + 1) * 64 * 4, stream);

    k_sw<<<(E_ + 255) / 256, 256, 0, stream>>>(w, sw);
    k_init<<<64, 256, 0, stream>>>(X, s0i, ii, r, ph, x, Sp, rr);

    dim3 gg(NIPP / 128, NIPP / 128);   // 31x31, lower triangle early-exits
    k_gemm<<<gg, 256, 0, stream>>>(d0, sw, ii, Sh);
    k_diag<<<(NIPP + 255) / 256, 256, 0, stream>>>(s0i, ii, Sh);

    for (int it = 0; it < NIT; ++it) {
        k_mvf<<<dim3(NIPP / 128, 2), 256, 0, stream>>>(Sh, ph, Sp);
        k_dot<<<64, 256, 0, stream>>>(ph, Sp, pAp + (size_t)it * 64);
        k_xr<<<64, 256, 0, stream>>>(rr + (size_t)it * 64, pAp + (size_t)it * 64,
                                     ph, Sp, x, r, rr + (size_t)(it + 1) * 64);
        k_p<<<(NIPP * B_ + 255) / 256, 256, 0, stream>>>(
            rr + (size_t)(it + 1) * 64, rr + (size_t)it * 64, r, ph, Sp);
    }

    k_out<<<(B_ * NI_ + 255) / 256, 256, 0, stream>>>(x, out);
}

// Round 3
// 2037.682 us; speedup vs baseline: 3.6715x; 3.6557x over previous
//
#include <hip/hip_runtime.h>
#include <math.h>

// V=4096, E=12288, NI=3900, B=64
#define NI_   3900
#define NIPP  3968            // NI padded to multiple of 128
#define E_    12288
#define B_    64
#define V_    4096
#define NIT   24              // CG iterations (kappa ~13)

typedef _Float16 f16x8 __attribute__((ext_vector_type(8)));
typedef float    f32x4 __attribute__((ext_vector_type(4)));

// ---------------------------------------------------------------------------
__global__ void k_sw(const float* __restrict__ w, float* __restrict__ sw) {
    int e = blockIdx.x * blockDim.x + threadIdx.x;
    if (e < E_) sw[e] = sqrtf(w[e]);
}

// AT[i][k] = f16( sw[k] * d0[k, ii[i]] ), zero-padded rows i >= NI_.
// 64k x 64i tile per block; LDS transpose; coalesced global read & write.
__global__ __launch_bounds__(256) void k_conv(const float* __restrict__ d0,
                                              const float* __restrict__ sw,
                                              const int* __restrict__ ii,
                                              _Float16* __restrict__ AT) {
    __shared__ _Float16 Ls[64][65];    // [k][i], pad 65 to spread banks
    int k0 = blockIdx.x * 64, i0 = blockIdx.y * 64;
    int t = threadIdx.x;
    int kr = t >> 4, ic = (t & 15) * 4;
    int g[4];
#pragma unroll
    for (int u = 0; u < 4; ++u) {
        int i = i0 + ic + u;
        g[u] = (i < NI_) ? ii[i] : -1;
    }
#pragma unroll
    for (int p = 0; p < 4; ++p) {
        int k = k0 + p * 16 + kr;
        float s = sw[k];
        const float* row = d0 + (size_t)k * V_;
#pragma unroll
        for (int u = 0; u < 4; ++u)
            Ls[p * 16 + kr][ic + u] = (_Float16)(g[u] >= 0 ? s * row[g[u]] : 0.f);
    }
    __syncthreads();
    int ir = t >> 3, kc = (t & 7) * 8;
#pragma unroll
    for (int p = 0; p < 2; ++p) {
        int i = p * 32 + ir;
        f16x8 v;
#pragma unroll
        for (int j = 0; j < 8; ++j) v[j] = Ls[kc + j][i];
        *(f16x8*)&AT[(size_t)(i0 + i) * E_ + k0 + kc] = v;
    }
}

// r = b = X[:,ii].T / s0i[ii];  ph = f16(r);  x = 0; Sp = 0; rr0[c] = sum r^2
__global__ void k_init(const float* __restrict__ X, const float* __restrict__ s0i,
                       const int* __restrict__ ii,
                       float* __restrict__ r, _Float16* __restrict__ ph,
                       float* __restrict__ x, float* __restrict__ Sp,
                       float* __restrict__ rr0) {
    __shared__ float red[4][64];
    int t = threadIdx.x, c = t & 63, g = t >> 6;
    float acc = 0.f;
    for (int i = blockIdx.x * 4 + g; i < NIPP; i += gridDim.x * 4) {
        float v = 0.f;
        if (i < NI_) { int gg = ii[i]; v = X[(size_t)c * V_ + gg] / s0i[gg]; }
        size_t o = (size_t)i * 64 + c;
        r[o] = v; ph[o] = (_Float16)v; x[o] = 0.f; Sp[o] = 0.f;
        acc += v * v;
    }
    red[g][c] = acc; __syncthreads();
    if (g == 0) atomicAdd(&rr0[c], red[0][c] + red[1][c] + red[2][c] + red[3][c]);
}

// ---------------------------------------------------------------------------
// Sh[i,j] = sum_k AT[i,k]*AT[j,k]   (f16 MFMA, reg-staged swizzled LDS)
// 128x128 tile / block, 4 waves (2x2 of 64x64), BK=64.
__global__ __launch_bounds__(256) void k_gemm(const _Float16* __restrict__ AT,
                                              _Float16* __restrict__ Sh) {
    int bi = blockIdx.y, bj = blockIdx.x;
    if (bj < bi) return;
    __shared__ _Float16 TA[128 * 64];   // [row][chunk^ (row&7)] swizzled, 16KB
    __shared__ _Float16 TB[128 * 64];
    int t = threadIdx.x;
    int l = t & 63, w = t >> 6;
    int gi = bi * 128, gj = bj * 128;
    int wr = (w >> 1) * 64, wc = (w & 1) * 64;

    int srow = t >> 3;          // 0..31 staging row within round
    int sch  = t & 7;           // 16B chunk 0..7
    int sslot = sch ^ (srow & 7);

    f16x8 ra[4], rb[4];
    f32x4 acc[4][4] = {};

#define LOADK(K0)                                                              \
    {                                                                          \
        _Pragma("unroll")                                                      \
        for (int rnd = 0; rnd < 4; ++rnd) {                                    \
            int row = rnd * 32 + srow;                                         \
            ra[rnd] = *(const f16x8*)&AT[(size_t)(gi + row) * E_ + (K0) + sch * 8]; \
            rb[rnd] = *(const f16x8*)&AT[(size_t)(gj + row) * E_ + (K0) + sch * 8]; \
        }                                                                      \
    }

    LOADK(0);
    for (int k0 = 0; k0 < E_; k0 += 64) {
        if (k0) __syncthreads();
#pragma unroll
        for (int rnd = 0; rnd < 4; ++rnd) {
            int row = rnd * 32 + srow;
            *(f16x8*)&TA[row * 64 + sslot * 8] = ra[rnd];
            *(f16x8*)&TB[row * 64 + sslot * 8] = rb[rnd];
        }
        __syncthreads();
        if (k0 + 64 < E_) LOADK(k0 + 64);
#pragma unroll
        for (int kk = 0; kk < 2; ++kk) {
            int kb = kk * 4 + (l >> 4);
            f16x8 a[4], b[4];
#pragma unroll
            for (int f = 0; f < 4; ++f) {
                int i = wr + f * 16 + (l & 15);
                a[f] = *(const f16x8*)&TA[i * 64 + ((kb ^ (i & 7)) << 3)];
                int j = wc + f * 16 + (l & 15);
                b[f] = *(const f16x8*)&TB[j * 64 + ((kb ^ (j & 7)) << 3)];
            }
#pragma unroll
            for (int fm = 0; fm < 4; ++fm)
#pragma unroll
                for (int fn = 0; fn < 4; ++fn)
                    acc[fm][fn] = __builtin_amdgcn_mfma_f32_16x16x32_f16(
                        a[fm], b[fn], acc[fm][fn], 0, 0, 0);
        }
    }
#undef LOADK
    // C/D layout: col = l&15, row = (l>>4)*4 + q
#pragma unroll
    for (int fm = 0; fm < 4; ++fm)
#pragma unroll
        for (int fn = 0; fn < 4; ++fn)
#pragma unroll
            for (int q = 0; q < 4; ++q) {
                int r = gi + wr + fm * 16 + (l >> 4) * 4 + q;
                int c = gj + wc + fn * 16 + (l & 15);
                _Float16 v = (_Float16)acc[fm][fn][q];
                Sh[(size_t)r * NIPP + c] = v;
                if (bi != bj) Sh[(size_t)c * NIPP + r] = v;
            }
}

// Sh[i,i] += 1/s0i[ii[i]]  (padded rows get identity)
__global__ void k_diag(const float* __restrict__ s0i, const int* __restrict__ ii,
                       _Float16* __restrict__ Sh) {
    int i = blockIdx.x * blockDim.x + threadIdx.x;
    if (i >= NIPP) return;
    float add = (i < NI_) ? 1.0f / s0i[ii[i]] : 1.0f;
    size_t o = (size_t)i * NIPP + i;
    Sh[o] = (_Float16)((float)Sh[o] + add);
}

// ---------------------------------------------------------------------------
// Sp += Sh[rows 128*bi ..][kchunk] @ ph
__global__ __launch_bounds__(256) void k_mvf(const _Float16* __restrict__ Sh,
                                             const _Float16* __restrict__ ph,
                                             float* __restrict__ Sp) {
    int bi = blockIdx.x;
    int ks = blockIdx.y;
    __shared__ _Float16 PT[64 * 64];
    int t = threadIdx.x;
    int l = t & 63, w = t >> 6;
    int r0 = bi * 128 + w * 32;
    int sc = t & 63, sq = t >> 6;
    f32x4 acc[2][4] = {};
    for (int k0 = ks * 1984; k0 < ks * 1984 + 1984; k0 += 64) {
#pragma unroll
        for (int p = 0; p < 2; ++p) {
            int kb = p * 4 + sq;
            f16x8 v;
#pragma unroll
            for (int j = 0; j < 8; ++j)
                v[j] = ph[(size_t)(k0 + kb * 8 + j) * 64 + sc];
            *(f16x8*)&PT[sc * 64 + ((kb ^ (sc & 7)) << 3)] = v;
        }
        __syncthreads();
#pragma unroll
        for (int kk = 0; kk < 2; ++kk) {
            int kb = kk * 4 + (l >> 4);
            int kg = k0 + kk * 32 + (l >> 4) * 8;
            f16x8 a[2], b[4];
#pragma unroll
            for (int f = 0; f < 2; ++f)
                a[f] = *(const f16x8*)&Sh[(size_t)(r0 + f * 16 + (l & 15)) * NIPP + kg];
#pragma unroll
            for (int f = 0; f < 4; ++f) {
                int j = f * 16 + (l & 15);
                b[f] = *(const f16x8*)&PT[j * 64 + ((kb ^ (j & 7)) << 3)];
            }
#pragma unroll
            for (int fm = 0; fm < 2; ++fm)
#pragma unroll
                for (int fn = 0; fn < 4; ++fn)
                    acc[fm][fn] = __builtin_amdgcn_mfma_f32_16x16x32_f16(
                        a[fm], b[fn], acc[fm][fn], 0, 0, 0);
        }
        __syncthreads();
    }
#pragma unroll
    for (int fm = 0; fm < 2; ++fm)
#pragma unroll
        for (int fn = 0; fn < 4; ++fn)
#pragma unroll
            for (int q = 0; q < 4; ++q) {
                int r = r0 + fm * 16 + (l >> 4) * 4 + q;
                int c = fn * 16 + (l & 15);
                atomicAdd(&Sp[(size_t)r * 64 + c], acc[fm][fn][q]);
            }
}

// out[c] += sum_i a[i,c]*b[i,c]
__global__ void k_dot(const _Float16* __restrict__ a, const float* __restrict__ b,
                      float* __restrict__ out) {
    __shared__ float red[4][64];
    int t = threadIdx.x, c = t & 63, g = t >> 6;
    float acc = 0.f;
    for (int i = blockIdx.x * 4 + g; i < NIPP; i += gridDim.x * 4) {
        size_t o = (size_t)i * 64 + c;
        acc += (float)a[o] * b[o];
    }
    red[g][c] = acc; __syncthreads();
    if (g == 0) atomicAdd(&out[c], red[0][c] + red[1][c] + red[2][c] + red[3][c]);
}

// alpha = rro/pAp; x += alpha*ph; r -= alpha*Sp; rrn[c] += sum r^2
__global__ void k_xr(const float* __restrict__ rro, const float* __restrict__ pApd,
                     const _Float16* __restrict__ ph, const float* __restrict__ Sp,
                     float* __restrict__ x, float* __restrict__ r,
                     float* __restrict__ rrn) {
    __shared__ float red[4][64];
    int t = threadIdx.x, c = t & 63, g = t >> 6;
    float alpha = rro[c] / (pApd[c] + 1e-30f);
    float acc = 0.f;
    for (int i = blockIdx.x * 4 + g; i < NIPP; i += gridDim.x * 4) {
        size_t o = (size_t)i * 64 + c;
        x[o] += alpha * (float)ph[o];
        float rn = r[o] - alpha * Sp[o];
        r[o] = rn;
        acc += rn * rn;
    }
    red[g][c] = acc; __syncthreads();
    if (g == 0) atomicAdd(&rrn[c], red[0][c] + red[1][c] + red[2][c] + red[3][c]);
}

// beta = rrn/rro; ph = f16(r + beta*ph); Sp = 0
__global__ void k_p(const float* __restrict__ rrn, const float* __restrict__ rro,
                    const float* __restrict__ r, _Float16* __restrict__ ph,
                    float* __restrict__ Sp) {
    int idx = blockIdx.x * blockDim.x + threadIdx.x;
    if (idx >= NIPP * B_) return;
    int c = idx & 63;
    float beta = rrn[c] / (rro[c] + 1e-30f);
    ph[idx] = (_Float16)(r[idx] + beta * (float)ph[idx]);
    Sp[idx] = 0.f;
}

// out[c, i] = x[i, c]
__global__ void k_out(const float* __restrict__ x, float* __restrict__ out) {
    int idx = blockIdx.x * blockDim.x + threadIdx.x;
    if (idx >= B_ * NI_) return;
    int c = idx / NI_, i = idx - c * NI_;
    out[idx] = x[(size_t)i * 64 + c];
}

// ---------------------------------------------------------------------------
extern "C" void kernel_launch(void* const* d_in, const int* in_sizes, int n_in,
                              void* d_out, int out_size, void* d_ws, size_t ws_size,
                              hipStream_t stream) {
    const float* X   = (const float*)d_in[0];
    const float* d0  = (const float*)d_in[1];
    const float* w   = (const float*)d_in[2];
    const float* s0i = (const float*)d_in[3];
    const int*   ii  = (const int*)d_in[4];
    float* out = (float*)d_out;

    char* ws = (char*)d_ws;
    size_t off = 0;
    _Float16* AT = (_Float16*)(ws + off); off += (size_t)NIPP * E_ * 2;     // 97.5MB
    _Float16* Sh = (_Float16*)(ws + off); off += (size_t)NIPP * NIPP * 2;   // 31.5MB
    _Float16* ph = (_Float16*)(ws + off); off += (size_t)NIPP * B_ * 2;
    float* Sp = (float*)(ws + off); off += (size_t)NIPP * B_ * 4;
    float* x  = (float*)(ws + off); off += (size_t)NIPP * B_ * 4;
    float* r  = (float*)(ws + off); off += (size_t)NIPP * B_ * 4;
    float* sw = (float*)(ws + off); off += (size_t)E_ * 4;
    float* rr  = (float*)(ws + off); off += (size_t)(NIT + 1) * 64 * 4;
    float* pAp = (float*)(ws + off); off += (size_t)NIT * 64 * 4;
    if (ws_size < off) return;   // clean failure signal

    hipMemsetAsync(rr, 0, (size_t)(2 * NIT + 1) * 64 * 4, stream);

    k_sw<<<(E_ + 255) / 256, 256, 0, stream>>>(w, sw);
    k_conv<<<dim3(E_ / 64, NIPP / 64), 256, 0, stream>>>(d0, sw, ii, AT);
    k_init<<<64, 256, 0, stream>>>(X, s0i, ii, r, ph, x, Sp, rr);

    dim3 gg(NIPP / 128, NIPP / 128);   // 31x31, lower triangle early-exits
    k_gemm<<<gg, 256, 0, stream>>>(AT, Sh);
    k_diag<<<(NIPP + 255) / 256, 256, 0, stream>>>(s0i, ii, Sh);

    for (int it = 0; it < NIT; ++it) {
        k_mvf<<<dim3(NIPP / 128, 2), 256, 0, stream>>>(Sh, ph, Sp);
        k_dot<<<64, 256, 0, stream>>>(ph, Sp, pAp + (size_t)it * 64);
        k_xr<<<64, 256, 0, stream>>>(rr + (size_t)it * 64, pAp + (size_t)it * 64,
                                     ph, Sp, x, r, rr + (size_t)(it + 1) * 64);
        k_p<<<(NIPP * B_ + 255) / 256, 256, 0, stream>>>(
            rr + (size_t)(it + 1) * 64, rr + (size_t)it * 64, r, ph, Sp);
    }

    k_out<<<(B_ * NI_ + 255) / 256, 256, 0, stream>>>(x, out);
}

// Round 4
// 1181.069 us; speedup vs baseline: 6.3344x; 1.7253x over previous
//
#include <hip/hip_runtime.h>
#include <math.h>

// V=4096, E=12288, NI=3900, B=64
#define NI_   3900
#define NIPP  4096            // NI padded to 4096 (nice divisibility)
#define E_    12288
#define B_    64
#define V_    4096
#define NIT   20              // CG iterations
#define KS_   8               // k-splits in matvec (512 k each)

typedef _Float16 f16x8 __attribute__((ext_vector_type(8)));
typedef float    f32x4 __attribute__((ext_vector_type(4)));

__device__ __forceinline__ void gload16(const void* g, void* lds) {
    // dest = wave-uniform LDS base + lane*16B ; src is per-lane
    __builtin_amdgcn_global_load_lds(
        (const __attribute__((address_space(1))) unsigned int*)g,
        (__attribute__((address_space(3))) unsigned int*)lds, 16, 0, 0);
}

// ---------------------------------------------------------------------------
__global__ void k_sw(const float* __restrict__ w, float* __restrict__ sw) {
    int e = blockIdx.x * blockDim.x + threadIdx.x;
    if (e < E_) sw[e] = sqrtf(w[e]);
}

// AT[i][k] = f16( sw[k] * d0[k, ii[i]] ), zero for i >= NI_.
__global__ __launch_bounds__(256) void k_conv(const float* __restrict__ d0,
                                              const float* __restrict__ sw,
                                              const int* __restrict__ ii,
                                              _Float16* __restrict__ AT) {
    __shared__ _Float16 Ls[64][65];
    int k0 = blockIdx.x * 64, i0 = blockIdx.y * 64;
    int t = threadIdx.x;
    int kr = t >> 4, ic = (t & 15) * 4;
    int g[4];
#pragma unroll
    for (int u = 0; u < 4; ++u) {
        int i = i0 + ic + u;
        g[u] = (i < NI_) ? ii[i] : -1;
    }
    bool cont = (g[0] >= 0) && (g[3] == g[0] + 3) && ((g[0] & 3) == 0);
#pragma unroll
    for (int p = 0; p < 4; ++p) {
        int k = k0 + p * 16 + kr;
        float s = sw[k];
        const float* row = d0 + (size_t)k * V_;
        if (cont) {
            float4 v4 = *(const float4*)&row[g[0]];
            Ls[p * 16 + kr][ic + 0] = (_Float16)(s * v4.x);
            Ls[p * 16 + kr][ic + 1] = (_Float16)(s * v4.y);
            Ls[p * 16 + kr][ic + 2] = (_Float16)(s * v4.z);
            Ls[p * 16 + kr][ic + 3] = (_Float16)(s * v4.w);
        } else {
#pragma unroll
            for (int u = 0; u < 4; ++u)
                Ls[p * 16 + kr][ic + u] = (_Float16)(g[u] >= 0 ? s * row[g[u]] : 0.f);
        }
    }
    __syncthreads();
    int ir = t >> 3, kc = (t & 7) * 8;
#pragma unroll
    for (int p = 0; p < 2; ++p) {
        int i = p * 32 + ir;
        f16x8 v;
#pragma unroll
        for (int j = 0; j < 8; ++j) v[j] = Ls[kc + j][i];
        *(f16x8*)&AT[(size_t)(i0 + i) * E_ + k0 + kc] = v;
    }
}

// c-major init: block c. r[c][i] = X[c,ii[i]]/s0i[ii[i]]; phT = f16(r); x=0;
// rr[c] = sum_i r^2 (block-local, no atomics).
__global__ __launch_bounds__(256) void k_init(const float* __restrict__ X,
                                              const float* __restrict__ s0i,
                                              const int* __restrict__ ii,
                                              float* __restrict__ r,
                                              _Float16* __restrict__ phT,
                                              float* __restrict__ x,
                                              float* __restrict__ rr) {
    __shared__ float red[4];
    int c = blockIdx.x, t = threadIdx.x;
    float acc = 0.f;
    for (int i = t; i < NIPP; i += 256) {
        float v = 0.f;
        if (i < NI_) { int g = ii[i]; v = X[(size_t)c * V_ + g] / s0i[g]; }
        size_t o = (size_t)c * NIPP + i;
        r[o] = v; phT[o] = (_Float16)v; x[o] = 0.f;
        acc += v * v;
    }
#pragma unroll
    for (int s = 32; s; s >>= 1) acc += __shfl_down(acc, s, 64);
    if ((t & 63) == 0) red[t >> 6] = acc;
    __syncthreads();
    if (t == 0) rr[c] = red[0] + red[1] + red[2] + red[3];
}

// ---------------------------------------------------------------------------
// Sh[i,j] = sum_k AT[i,k]*AT[j,k].  m97 structure: global_load_lds staging,
// linear LDS, 2-barrier K-loop, 128x128 tile, 4 waves, BK=64.
// 1-D triangular grid (528 tiles) with bijective XCD swizzle.
__global__ __launch_bounds__(256) void k_gemm(const _Float16* __restrict__ AT,
                                              _Float16* __restrict__ Sh) {
    int wg = blockIdx.x;
    int swz = (wg & 7) * 66 + (wg >> 3);        // 528 = 8*66, bijective
    int bi = 0, rem = swz;
    while (rem >= 32 - bi) { rem -= 32 - bi; ++bi; }
    int bj = bi + rem;

    __shared__ _Float16 TA[128 * 64];   // [row][k] linear
    __shared__ _Float16 TB[128 * 64];
    int t = threadIdx.x, l = t & 63, w = t >> 6;
    int gi = bi * 128, gj = bj * 128;
    int wr = (w >> 1) * 64, wc = (w & 1) * 64;
    int lr = l >> 3, lc = (l & 7) * 8;          // gload lane: row-in-8, k-elem

    f32x4 acc[4][4] = {};

    for (int k0 = 0; k0 < E_; k0 += 64) {
        if (k0) __syncthreads();                // LDS consumed before overwrite
#pragma unroll
        for (int inst = 0; inst < 4; ++inst) {  // wave w stages rows w*32..+32
            int row = w * 32 + inst * 8;
            gload16(&AT[(size_t)(gi + row + lr) * E_ + k0 + lc], &TA[row * 64]);
            gload16(&AT[(size_t)(gj + row + lr) * E_ + k0 + lc], &TB[row * 64]);
        }
        __syncthreads();                        // drains vmcnt before barrier
#pragma unroll
        for (int kk = 0; kk < 2; ++kk) {
            int ko = kk * 32 + (l >> 4) * 8;
            f16x8 a[4], b[4];
#pragma unroll
            for (int f = 0; f < 4; ++f) {
                a[f] = *(const f16x8*)&TA[(wr + f * 16 + (l & 15)) * 64 + ko];
                b[f] = *(const f16x8*)&TB[(wc + f * 16 + (l & 15)) * 64 + ko];
            }
#pragma unroll
            for (int fm = 0; fm < 4; ++fm)
#pragma unroll
                for (int fn = 0; fn < 4; ++fn)
                    acc[fm][fn] = __builtin_amdgcn_mfma_f32_16x16x32_f16(
                        a[fm], b[fn], acc[fm][fn], 0, 0, 0);
        }
    }
    // C/D layout: col = l&15, row = (l>>4)*4 + q  (verified R2/R3)
#pragma unroll
    for (int fm = 0; fm < 4; ++fm)
#pragma unroll
        for (int fn = 0; fn < 4; ++fn)
#pragma unroll
            for (int q = 0; q < 4; ++q) {
                int r = gi + wr + fm * 16 + (l >> 4) * 4 + q;
                int c = gj + wc + fn * 16 + (l & 15);
                _Float16 v = (_Float16)acc[fm][fn][q];
                Sh[(size_t)r * NIPP + c] = v;
                if (bi != bj) Sh[(size_t)c * NIPP + r] = v;
            }
}

// Sh[i,i] += 1/s0i[ii[i]]  (padded rows get identity)
__global__ void k_diag(const float* __restrict__ s0i, const int* __restrict__ ii,
                       _Float16* __restrict__ Sh) {
    int i = blockIdx.x * blockDim.x + threadIdx.x;
    if (i >= NIPP) return;
    float add = (i < NI_) ? 1.0f / s0i[ii[i]] : 1.0f;
    size_t o = (size_t)i * NIPP + i;
    Sh[o] = (_Float16)((float)Sh[o] + add);
}

// ---------------------------------------------------------------------------
// part[ks][c][r] = (Sh[rows rt*64..][k-split ks] @ p)  — LDS-free MFMA matvec.
// Grid (64,8); wave w of block rt owns rows rt*64+w*16..+16. Non-atomic.
__global__ __launch_bounds__(256) void k_mv(const _Float16* __restrict__ Sh,
                                            const _Float16* __restrict__ phT,
                                            float* __restrict__ part) {
    int rt = blockIdx.x, ks = blockIdx.y;
    int t = threadIdx.x, l = t & 63, w = t >> 6;
    int r0 = rt * 64 + w * 16;
    int lrow = l & 15, lko = (l >> 4) * 8;
    const _Float16* arow = Sh + (size_t)(r0 + lrow) * NIPP + ks * 512 + lko;
    f32x4 acc[4] = {};
#pragma unroll 4
    for (int kk = 0; kk < 16; ++kk) {
        f16x8 a = *(const f16x8*)(arow + kk * 32);
#pragma unroll
        for (int fn = 0; fn < 4; ++fn) {
            f16x8 b = *(const f16x8*)&phT[(size_t)(fn * 16 + lrow) * NIPP +
                                          ks * 512 + kk * 32 + lko];
            acc[fn] = __builtin_amdgcn_mfma_f32_16x16x32_f16(a, b, acc[fn], 0, 0, 0);
        }
    }
#pragma unroll
    for (int fn = 0; fn < 4; ++fn) {
        int c = fn * 16 + lrow;
        *(f32x4*)&part[(size_t)(ks * 64 + c) * NIPP + r0 + (l >> 4) * 4] = acc[fn];
    }
}

// One block per batch column c: pAp -> alpha -> x,r update -> rr -> beta -> p.
// All reductions block-local; rr[c] is read (old) then overwritten (new).
__global__ __launch_bounds__(256) void k_fused(const float* __restrict__ part,
                                               _Float16* __restrict__ phT,
                                               float* __restrict__ x,
                                               float* __restrict__ r,
                                               float* __restrict__ rr) {
    __shared__ float red1[4], red2[4];
    int c = blockIdx.x, t = threadIdx.x;
    float rro = rr[c];
    size_t cb = (size_t)c * NIPP;

    // phase A: pAp
    float pap = 0.f;
    for (int i = t; i < NIPP; i += 256) {
        float sp = 0.f;
#pragma unroll
        for (int ks = 0; ks < KS_; ++ks) sp += part[(size_t)(ks * 64 + c) * NIPP + i];
        pap += (float)phT[cb + i] * sp;
    }
#pragma unroll
    for (int s = 32; s; s >>= 1) pap += __shfl_down(pap, s, 64);
    if ((t & 63) == 0) red1[t >> 6] = pap;
    __syncthreads();
    float alpha = rro / (red1[0] + red1[1] + red1[2] + red1[3] + 1e-30f);

    // phase B: x += alpha p; r -= alpha Sp; rrn = ||r||^2
    float rrn = 0.f;
    for (int i = t; i < NIPP; i += 256) {
        float sp = 0.f;
#pragma unroll
        for (int ks = 0; ks < KS_; ++ks) sp += part[(size_t)(ks * 64 + c) * NIPP + i];
        float pv = (float)phT[cb + i];
        x[cb + i] += alpha * pv;
        float rn = r[cb + i] - alpha * sp;
        r[cb + i] = rn;
        rrn += rn * rn;
    }
#pragma unroll
    for (int s = 32; s; s >>= 1) rrn += __shfl_down(rrn, s, 64);
    if ((t & 63) == 0) red2[t >> 6] = rrn;
    __syncthreads();
    float rrnt = red2[0] + red2[1] + red2[2] + red2[3];
    if (t == 0) rr[c] = rrnt;
    float beta = rrnt / (rro + 1e-30f);

    // phase C: p = r + beta p
    for (int i = t; i < NIPP; i += 256)
        phT[cb + i] = (_Float16)(r[cb + i] + beta * (float)phT[cb + i]);
}

// out[c, i] = x[c][i]  (c-major: plain coalesced copy)
__global__ void k_out(const float* __restrict__ x, float* __restrict__ out) {
    int c = blockIdx.x, t = threadIdx.x;
    for (int i = t; i < NI_; i += 256)
        out[(size_t)c * NI_ + i] = x[(size_t)c * NIPP + i];
}

// ---------------------------------------------------------------------------
extern "C" void kernel_launch(void* const* d_in, const int* in_sizes, int n_in,
                              void* d_out, int out_size, void* d_ws, size_t ws_size,
                              hipStream_t stream) {
    const float* X   = (const float*)d_in[0];
    const float* d0  = (const float*)d_in[1];
    const float* w   = (const float*)d_in[2];
    const float* s0i = (const float*)d_in[3];
    const int*   ii  = (const int*)d_in[4];
    float* out = (float*)d_out;

    char* ws = (char*)d_ws;
    size_t off = 0;
    _Float16* AT = (_Float16*)(ws + off); off += (size_t)NIPP * E_ * 2;     // 100.7MB
    _Float16* Sh = (_Float16*)(ws + off); off += (size_t)NIPP * NIPP * 2;   // 33.5MB
    _Float16* phT = (_Float16*)(ws + off); off += (size_t)NIPP * B_ * 2;
    float* x  = (float*)(ws + off); off += (size_t)NIPP * B_ * 4;
    float* r  = (float*)(ws + off); off += (size_t)NIPP * B_ * 4;
    float* sw = (float*)(ws + off); off += (size_t)E_ * 4;
    float* rr = (float*)(ws + off); off += 64 * 4;
    // part (8 MB) aliases AT — AT is dead after k_gemm.
    float* part = (float*)AT;
    if (ws_size < off) return;   // clean failure signal

    k_sw<<<(E_ + 255) / 256, 256, 0, stream>>>(w, sw);
    k_conv<<<dim3(E_ / 64, NIPP / 64), 256, 0, stream>>>(d0, sw, ii, AT);
    k_init<<<64, 256, 0, stream>>>(X, s0i, ii, r, phT, x, rr);

    k_gemm<<<528, 256, 0, stream>>>(AT, Sh);
    k_diag<<<(NIPP + 255) / 256, 256, 0, stream>>>(s0i, ii, Sh);

    for (int it = 0; it < NIT; ++it) {
        k_mv<<<dim3(NIPP / 64, KS_), 256, 0, stream>>>(Sh, phT, part);
        k_fused<<<64, 256, 0, stream>>>(part, phT, x, r, rr);
    }

    k_out<<<64, 256, 0, stream>>>(x, out);
}